// Round 3
// baseline (876.854 us; speedup 1.0000x reference)
//
#include <hip/hip_runtime.h>
#include <hip/hip_bf16.h>

// FFNPCCNorm: out[n,o] = max( (xc[n]·wc[o]) / (|xc[n]| |wc[o]|), 1e-10 ) + bias[o]
// with xc = x - rowmean(x), wc = w - rowmean(w).
// Identities: sum(wc[o,:]) == 0  =>  xc·wc == x·wc ; 1/|wc| folded into bf16 B;
// 1/|xc| applied fp32 in the epilogue.
//
// v3b: barrier-free streaming (v3 + staging stride fix). Full B panel
// (256x256 bf16, pad-8 stride) staged in LDS once per block (one
// __syncthreads, then none). Each wave independently streams 16-row x
// chunks: global->reg loads, norms+bf16 cvt in-register (swapped-MFMA D
// layout puts x-row on lane&15 == the shfl-reduce group, so norms never
// touch LDS), 128 ds_read_b128 + 128 MFMA, nontemporal dwordx4 stores.
// Waves continuously re-issue memory -> HBM stays saturated.

#define K_DIM  256
#define N_OUT  256
#define LDSW   264          // B row stride in shorts (256 + 8 pad): 33x16B, odd
#define CHUNKS 4            // 16-row chunks per wave
#define NBLK   512          // 512 blk * 8 waves * 64 rows = 262144

typedef __attribute__((ext_vector_type(8))) __bf16 bf16x8;
typedef __attribute__((ext_vector_type(8))) unsigned short u16x8;
typedef __attribute__((ext_vector_type(4))) float  f32x4;

__device__ __forceinline__ unsigned short f2bf(float f) {
    union { float f; unsigned u; } v; v.f = f;
    unsigned r = v.u + 0x7FFFu + ((v.u >> 16) & 1u);   // RNE
    return (unsigned short)(r >> 16);
}

// One wave per weight row: wc = (w - mean) * rsqrt(sum(wc^2)), stored bf16.
__global__ __launch_bounds__(64) void prep_w(const float* __restrict__ w,
                                             unsigned short* __restrict__ wcb) {
    int o = blockIdx.x;        // 256 rows
    int lane = threadIdx.x;    // 64 lanes, 4 floats each
    f32x4 v = *((const f32x4*)(w + (size_t)o * K_DIM) + lane);
    float s  = v.x + v.y + v.z + v.w;
    float s2 = v.x*v.x + v.y*v.y + v.z*v.z + v.w*v.w;
#pragma unroll
    for (int off = 32; off >= 1; off >>= 1) {
        s  += __shfl_xor(s,  off);
        s2 += __shfl_xor(s2, off);
    }
    float mean  = s * (1.0f / 256.0f);
    float var   = s2 - s * mean;                 // sum((w-mean)^2)
    float scale = rsqrtf(fmaxf(var, 1e-30f));
    ushort4 b;
    b.x = f2bf((v.x - mean) * scale);
    b.y = f2bf((v.y - mean) * scale);
    b.z = f2bf((v.z - mean) * scale);
    b.w = f2bf((v.w - mean) * scale);
    *(ushort4*)(wcb + (size_t)o * K_DIM + lane * 4) = b;
}

__global__ __launch_bounds__(512, 2) void pcc_gemm(const float* __restrict__ x,
                                                   const unsigned short* __restrict__ wcb,
                                                   const float* __restrict__ bias,
                                                   float* __restrict__ out) {
    __shared__ __align__(16) unsigned short bs[256 * LDSW];  // 135168 B
    __shared__ __align__(16) float bias_s[N_OUT];            // 1 KB

    const int t    = threadIdx.x;
    const int w    = t >> 6;           // wave 0..7
    const int lane = t & 63;
    const int l15  = lane & 15;
    const int q    = lane >> 4;

    // ---- stage B + bias into LDS (once). 512 threads: row = t>>1, half = t&1.
    // Each thread copies its 128-short half-row as 16 x 16B vectors (stride 8!).
    {
        const int r = t >> 1, h = t & 1;
        const unsigned short* src = wcb + (size_t)r * K_DIM + h * 128;
        unsigned short* dst = bs + r * LDSW + h * 128;
#pragma unroll
        for (int j = 0; j < 16; ++j)
            *(u16x8*)(dst + j * 8) = *(const u16x8*)(src + j * 8);
        if (t < 64) *(f32x4*)(bias_s + t * 4) = *(const f32x4*)(bias + t * 4);
    }
    __syncthreads();   // only barrier in the kernel

    const size_t wrow0 = ((size_t)blockIdx.x * 8 + w) * (16 * CHUNKS);

#pragma unroll 1
    for (int c = 0; c < CHUNKS; ++c) {
        const size_t row = wrow0 + c * 16 + l15;          // this lane's x row
        const float* rp = x + row * K_DIM + q * 8;        // A-frag k-offset

        // ---- load 64 floats (frag layout: k = q*8 + ks*32), norm + cvt on the fly
        bf16x8 af[8];
        float s = 0.f, s2 = 0.f;
#pragma unroll
        for (int ks = 0; ks < 8; ++ks) {
            f32x4 lo = *(const f32x4*)(rp + ks * 32);
            f32x4 hi = *(const f32x4*)(rp + ks * 32 + 4);
            s += lo.x + lo.y + lo.z + lo.w;
            s += hi.x + hi.y + hi.z + hi.w;
            s2 = fmaf(lo.x, lo.x, s2); s2 = fmaf(lo.y, lo.y, s2);
            s2 = fmaf(lo.z, lo.z, s2); s2 = fmaf(lo.w, lo.w, s2);
            s2 = fmaf(hi.x, hi.x, s2); s2 = fmaf(hi.y, hi.y, s2);
            s2 = fmaf(hi.z, hi.z, s2); s2 = fmaf(hi.w, hi.w, s2);
            bf16x8 a;
            a[0] = (__bf16)lo.x; a[1] = (__bf16)lo.y;
            a[2] = (__bf16)lo.z; a[3] = (__bf16)lo.w;
            a[4] = (__bf16)hi.x; a[5] = (__bf16)hi.y;
            a[6] = (__bf16)hi.z; a[7] = (__bf16)hi.w;
            af[ks] = a;
        }
        // row stats live on the 4 q-lanes sharing l15: reduce across q only
        s  += __shfl_xor(s, 16);  s  += __shfl_xor(s, 32);
        s2 += __shfl_xor(s2, 16); s2 += __shfl_xor(s2, 32);
        const float inv = rsqrtf(fmaxf(s2 - s * s * (1.0f / 256.0f), 1e-30f));

        // ---- MFMA: 16 rows x 256 cols = 16 tiles; B frags from LDS each chunk
        f32x4 acc[16];
#pragma unroll
        for (int ni = 0; ni < 16; ++ni) acc[ni] = (f32x4){0.f, 0.f, 0.f, 0.f};

        const unsigned short* bbase = bs + l15 * LDSW + q * 8;
#pragma unroll
        for (int ks = 0; ks < 8; ++ks) {
#pragma unroll
            for (int ni = 0; ni < 16; ++ni) {
                bf16x8 b = *(const bf16x8*)(bbase + ni * 16 * LDSW + ks * 32);
                // swapped operands: D col(lane&15) = x row, D row(q*4+r) = w row
                acc[ni] = __builtin_amdgcn_mfma_f32_16x16x32_bf16(b, af[ks], acc[ni], 0, 0, 0);
            }
        }

        // ---- epilogue: lane owns out[row][ni*16 + q*4 .. +3] -> dwordx4 NT stores
        float* op = out + row * N_OUT + q * 4;
#pragma unroll
        for (int ni = 0; ni < 16; ++ni) {
            f32x4 bv = *(const f32x4*)(bias_s + ni * 16 + q * 4);  // broadcast read
            f32x4 vx;
#pragma unroll
            for (int r = 0; r < 4; ++r)
                vx[r] = fmaxf(acc[ni][r] * inv, 1e-10f) + bv[r];
            __builtin_nontemporal_store(vx, (f32x4*)(op + ni * 16));
        }
    }
}

extern "C" void kernel_launch(void* const* d_in, const int* in_sizes, int n_in,
                              void* d_out, int out_size, void* d_ws, size_t ws_size,
                              hipStream_t stream) {
    const float* x    = (const float*)d_in[0];   // [262144, 256]
    const float* w    = (const float*)d_in[1];   // [256, 256]
    const float* bias = (const float*)d_in[2];   // [256]
    float* out = (float*)d_out;                  // [262144, 256]
    unsigned short* wcb = (unsigned short*)d_ws; // 128 KB bf16 wc (scaled)

    prep_w<<<256, 64, 0, stream>>>(w, wcb);
    pcc_gemm<<<NBLK, 512, 0, stream>>>(x, wcb, bias, out);
}